// Round 9
// baseline (698.022 us; speedup 1.0000x reference)
//
#include <hip/hip_runtime.h>
#include <cstdint>
#include <cstddef>

using u16 = unsigned short;
using u32 = unsigned int;

typedef __bf16 bf16x8 __attribute__((ext_vector_type(8)));
typedef float f32x4 __attribute__((ext_vector_type(4)));

#define DEV static __device__ __forceinline__

DEV u16 f2bf(float f) {
  u32 u = __builtin_bit_cast(u32, f);
  u32 r = (u + 0x7fffu + ((u >> 16) & 1u)) >> 16;   // RNE
  return (u16)r;
}
DEV float bf2f(u16 u) { return __builtin_bit_cast(float, ((u32)u) << 16); }

DEV void gload_lds16(const void* g, void* l) {
  __builtin_amdgcn_global_load_lds(
      (__attribute__((address_space(1))) void*)(void*)g,
      (__attribute__((address_space(3))) void*)l, 16, 0, 0);
}

// ---------------- fp32 -> bf16 elementwise ----------------
__global__ __launch_bounds__(256) void k_f2bf(const float* __restrict__ in,
                                              u16* __restrict__ out, int n8) {
  int tid = blockIdx.x * 256 + threadIdx.x;
  int nt = gridDim.x * 256;
  for (int i = tid; i < n8; i += nt) {
    const float4* p = (const float4*)(in + (size_t)i * 8);
    float4 a = p[0], b = p[1];
    u32 w0 = (u32)f2bf(a.x) | ((u32)f2bf(a.y) << 16);
    u32 w1 = (u32)f2bf(a.z) | ((u32)f2bf(a.w) << 16);
    u32 w2 = (u32)f2bf(b.x) | ((u32)f2bf(b.y) << 16);
    u32 w3 = (u32)f2bf(b.z) | ((u32)f2bf(b.w) << 16);
    *(uint4*)(out + (size_t)i * 8) = make_uint4(w0, w1, w2, w3);
  }
}

// ------------- fp32 W[k][n] -> bf16 WT[n][k] (64x64 LDS tiles) -------------
// tile stride 66 u16: 8-row read step = 264 words ≡ 8 mod 32 -> 2-way (was 8-way)
__global__ __launch_bounds__(256) void k_convT(const float* __restrict__ W,
                                               u16* __restrict__ WT,
                                               int ncols, int krows) {
  __shared__ u16 tile[64 * 66];
  int r0 = blockIdx.x * 64, c0 = blockIdx.y * 64;
  int t = threadIdx.x;
#pragma unroll
  for (int i = 0; i < 4; ++i) {
    int slot = i * 256 + t;
    int r = slot >> 4, c = (slot & 15) * 4;
    float4 v = *(const float4*)(W + (size_t)(r0 + r) * ncols + c0 + c);
    tile[r * 66 + c] = f2bf(v.x);
    tile[r * 66 + c + 1] = f2bf(v.y);
    tile[r * 66 + c + 2] = f2bf(v.z);
    tile[r * 66 + c + 3] = f2bf(v.w);
  }
  __syncthreads();
#pragma unroll
  for (int i = 0; i < 2; ++i) {
    int slot = i * 256 + t;
    int c = slot >> 3, rr = (slot & 7) * 8;
    u32 w[4];
#pragma unroll
    for (int j = 0; j < 4; ++j) {
      u16 lo = tile[(rr + 2 * j) * 66 + c];
      u16 hi = tile[(rr + 2 * j + 1) * 66 + c];
      w[j] = (u32)lo | ((u32)hi << 16);
    }
    *(uint4*)(WT + (size_t)(c0 + c) * krows + r0 + rr) =
        make_uint4(w[0], w[1], w[2], w[3]);
  }
}

// =============== 256x256 4-phase bf16 GEMM (T2+T3+T4+T5) ===============
// v4: merged phases (32 MFMA/phase), 4 barriers/iter, waits 2x vmcnt(4)
// placed pre-barrier (publish chain: wait -> barrier -> read).
#define VM4 asm volatile("s_waitcnt vmcnt(4)" ::: "memory")
#define VM0 asm volatile("s_waitcnt vmcnt(0)" ::: "memory")

template <bool OUT_BF16>
__global__ __launch_bounds__(512, 2) void k_gemm256(const u16* __restrict__ A,
                                                    const u16* __restrict__ BT,
                                                    void* __restrict__ Cout,
                                                    int N, int K, int grid_m) {
  __shared__ __align__(16) u16 Asmem[2][16384];  // [buf][256 rows][64 k] swizzled
  __shared__ __align__(16) u16 Bsmem[2][16384];
  const int nwg = gridDim.x;
  const int cpx = nwg >> 3;
  const int wg = (blockIdx.x & 7) * cpx + (blockIdx.x >> 3);
  const int row0 = (wg % grid_m) * 256;
  const int col0 = (wg / grid_m) * 256;
  const int tid = threadIdx.x;
  const int lane = tid & 63, wave = tid >> 6;
  const int wm = wave >> 2, wn = wave & 3;  // 2 x 4
  const int fr = lane & 15, fg = lane >> 4;
  const int NT = K >> 6;

  const int r_l0 = tid >> 3;
  const int gl = (tid & 7) ^ (r_l0 & 7);  // pre-swizzled logical granule

#define STAGE_A(b, h, s)                                                          \
  do {                                                                            \
    const u16* src_ = A + (size_t)(row0 + (h)*128 + r_l0) * K + (s)*64 + gl * 8;  \
    gload_lds16(src_, &Asmem[b][(h)*8192 + tid * 8]);                             \
    gload_lds16(src_ + (size_t)64 * K, &Asmem[b][(h)*8192 + 4096 + tid * 8]);     \
  } while (0)
#define STAGE_B(b, h, s)                                                          \
  do {                                                                            \
    const u16* src_ = BT + (size_t)(col0 + (h)*128 + r_l0) * K + (s)*64 + gl * 8; \
    gload_lds16(src_, &Bsmem[b][(h)*8192 + tid * 8]);                             \
    gload_lds16(src_ + (size_t)64 * K, &Bsmem[b][(h)*8192 + 4096 + tid * 8]);     \
  } while (0)

  const int aBase = (wm * 64 + fr) * 64;
  const int bBase = (wn * 32 + fr) * 64;
  const int sg0 = ((fg) ^ (fr & 7)) * 8;
  const int sg1 = ((4 + fg) ^ (fr & 7)) * 8;
#define LDA(buf, mh, m, kk) \
  (*(const bf16x8*)(&Asmem[buf][aBase + (mh)*8192 + (m)*1024 + ((kk) ? sg1 : sg0)]))
#define LDB(buf, nh, n, kk) \
  (*(const bf16x8*)(&Bsmem[buf][bBase + (nh)*8192 + (n)*1024 + ((kk) ? sg1 : sg0)]))

  bf16x8 a[4][2], b0[2][2], b1[2][2];
  f32x4 acc[2][2][4][2] = {};

  // Merged phase: {STG x2; reads A (+B if RDB); WT; barrier; 32 MFMA}.
#define PHASE2(buf, mh, RDB, STG1, STG2, WT)                                       \
  {                                                                                \
    STG1;                                                                          \
    STG2;                                                                          \
    _Pragma("unroll") for (int m_ = 0; m_ < 4; ++m_) {                             \
      a[m_][0] = LDA(buf, mh, m_, 0);                                              \
      a[m_][1] = LDA(buf, mh, m_, 1);                                              \
    }                                                                              \
    if (RDB) {                                                                     \
      _Pragma("unroll") for (int n_ = 0; n_ < 2; ++n_) {                           \
        b0[n_][0] = LDB(buf, 0, n_, 0);                                            \
        b0[n_][1] = LDB(buf, 0, n_, 1);                                            \
        b1[n_][0] = LDB(buf, 1, n_, 0);                                            \
        b1[n_][1] = LDB(buf, 1, n_, 1);                                            \
      }                                                                            \
    }                                                                              \
    WT;                                                                            \
    __builtin_amdgcn_s_barrier();                                                  \
    __builtin_amdgcn_s_setprio(1);                                                 \
    _Pragma("unroll") for (int m_ = 0; m_ < 4; ++m_) {                             \
      _Pragma("unroll") for (int n_ = 0; n_ < 2; ++n_) {                           \
        acc[mh][0][m_][n_] = __builtin_amdgcn_mfma_f32_16x16x32_bf16(              \
            a[m_][0], b0[n_][0], acc[mh][0][m_][n_], 0, 0, 0);                     \
        acc[mh][0][m_][n_] = __builtin_amdgcn_mfma_f32_16x16x32_bf16(              \
            a[m_][1], b0[n_][1], acc[mh][0][m_][n_], 0, 0, 0);                     \
        acc[mh][1][m_][n_] = __builtin_amdgcn_mfma_f32_16x16x32_bf16(              \
            a[m_][0], b1[n_][0], acc[mh][1][m_][n_], 0, 0, 0);                     \
        acc[mh][1][m_][n_] = __builtin_amdgcn_mfma_f32_16x16x32_bf16(              \
            a[m_][1], b1[n_][1], acc[mh][1][m_][n_], 0, 0, 0);                     \
      }                                                                            \
    }                                                                              \
    __builtin_amdgcn_s_setprio(0);                                                 \
  }

  // prologue: buf0 all halves + buf1.h0 (12 loads); retire buf0 (8), keep 4.
  STAGE_A(0, 0, 0); STAGE_B(0, 0, 0);
  STAGE_A(0, 1, 0); STAGE_B(0, 1, 0);
  STAGE_A(1, 0, 1); STAGE_B(1, 0, 1);
  VM4;
  __builtin_amdgcn_s_barrier();

  const int nIt = NT >> 1;
  for (int it = 0; it < nIt; ++it) {
    const int T = 2 * it;
    const int s2 = (T + 2 < NT) ? T + 2 : T;  // tail-clamped (benign rewrite)
    const int s3 = (T + 3 < NT) ? T + 3 : T;
    PHASE2(0, 0, true,  STAGE_A(1, 1, T + 1), STAGE_B(1, 1, T + 1), ((void)0));
    PHASE2(0, 1, false, STAGE_A(0, 0, s2),    STAGE_B(0, 0, s2),    VM4);
    PHASE2(1, 0, true,  STAGE_A(0, 1, s2),    STAGE_B(0, 1, s2),    ((void)0));
    PHASE2(1, 1, false, STAGE_A(1, 0, s3),    STAGE_B(1, 0, s3),    VM4);
  }
  VM0;

#pragma unroll
  for (int mh = 0; mh < 2; ++mh)
#pragma unroll
    for (int nh = 0; nh < 2; ++nh)
#pragma unroll
      for (int m = 0; m < 4; ++m) {
        const int growb = row0 + mh * 128 + wm * 64 + m * 16 + fg * 4;
#pragma unroll
        for (int rr = 0; rr < 4; ++rr) {
#pragma unroll
          for (int n = 0; n < 2; ++n) {
            const int gcol = col0 + nh * 128 + wn * 32 + n * 16 + fr;
            if (OUT_BF16)
              ((u16*)Cout)[(size_t)(growb + rr) * N + gcol] = f2bf(acc[mh][nh][m][n][rr]);
            else
              ((float*)Cout)[(size_t)(growb + rr) * N + gcol] = acc[mh][nh][m][n][rr];
          }
        }
      }
#undef PHASE2
#undef LDA
#undef LDB
#undef STAGE_A
#undef STAGE_B
}

// ---------------- RoPE trig table: T[s][0..63]=cos, [64..127]=sin ----------------
__global__ __launch_bounds__(128) void k_trig(float* __restrict__ T) {
  const int s = blockIdx.x;
  const int t = threadIdx.x;
  float inv = powf(10000.0f, -(float)(t & 63) * (1.0f / 64.0f));
  float ang = (float)s * inv;
  T[(size_t)s * 128 + t] = (t < 64) ? cosf(ang) : sinf(ang);
}

// ---------------- RoPE + head-major relayout for Q,K (vectorized) ----------------
__global__ __launch_bounds__(256) void k_rope(const u16* __restrict__ qkv,
                                              const float* __restrict__ T,
                                              u16* __restrict__ Qh,
                                              u16* __restrict__ Kh) {
  const int row = blockIdx.x;  // b*2048 + s
  const int s = row & 2047;
  const int b = row >> 11;
  const int t = threadIdx.x;
  __shared__ float cs[64], sn[64];
  if (t < 128) {
    float v = T[(size_t)s * 128 + t];
    if (t < 64) cs[t] = v; else sn[t - 64] = v;
  }
  __syncthreads();
  const int h = t >> 3, seg = t & 7;
  const float qscale = 0.08838834764831845f;  // 1/sqrt(128)
  const size_t base = (size_t)row * 12288 + h * 128 + seg * 8;
  const size_t obase = ((size_t)(b * 32 + h) * 2048 + s) * 128 + seg * 8;

#pragma unroll
  for (int mat = 0; mat < 2; ++mat) {  // 0 = Q, 1 = K
    const u16* src = qkv + base + mat * 4096;
    u16* dst = (mat == 0 ? Qh : Kh);
    const float sc = (mat == 0) ? qscale : 1.0f;
    uint4 lo = *(const uint4*)(src);
    uint4 hi = *(const uint4*)(src + 64);
    const u16* x1 = (const u16*)&lo;
    const u16* x2 = (const u16*)&hi;
    u16 o1[8], o2[8];
#pragma unroll
    for (int k = 0; k < 8; ++k) {
      float c = cs[seg * 8 + k], sv = sn[seg * 8 + k];
      float a = bf2f(x1[k]), d = bf2f(x2[k]);
      o1[k] = f2bf((a * c - d * sv) * sc);
      o2[k] = f2bf((d * c + a * sv) * sc);
    }
    *(uint4*)(dst + obase) = *(const uint4*)o1;
    *(uint4*)(dst + obase + 64) = *(const uint4*)o2;
  }
}

// ---------------- V relayout+transpose: qkv V -> VTh [64][128][2048] ----------------
__global__ __launch_bounds__(256) void k_vtrans(const u16* __restrict__ qkv,
                                                u16* __restrict__ VTh) {
  __shared__ u16 tile[64 * 136];
  const int hb = blockIdx.x;  // 0..63
  const int st = blockIdx.y;  // 0..31
  const int b = hb >> 5, h = hb & 31;
  const int t = threadIdx.x;
#pragma unroll
  for (int i = 0; i < 4; ++i) {
    int slot = i * 256 + t;
    int r = slot >> 4, c = (slot & 15) * 8;
    *(uint4*)(tile + r * 136 + c) =
        *(const uint4*)(qkv + (size_t)(b * 2048 + st * 64 + r) * 12288 + 8192 + h * 128 + c);
  }
  __syncthreads();
#pragma unroll
  for (int i = 0; i < 4; ++i) {
    int slot = i * 256 + t;
    int d = slot >> 3, c2 = (slot & 7) * 8;
    u32 w[4];
#pragma unroll
    for (int j = 0; j < 4; ++j) {
      u16 lo = tile[(c2 + 2 * j) * 136 + d];
      u16 hi = tile[(c2 + 2 * j + 1) * 136 + d];
      w[j] = (u32)lo | ((u32)hi << 16);
    }
    *(uint4*)(VTh + ((size_t)hb * 128 + d) * 2048 + st * 64 + c2) =
        make_uint4(w[0], w[1], w[2], w[3]);
  }
}

// ---------------- causal flash attention, QBLK=128, pipelined staging ----------------
__global__ __launch_bounds__(256, 2) void k_attn(const u16* __restrict__ Qh,
                                                 const u16* __restrict__ Kh,
                                                 const u16* __restrict__ VTh,
                                                 u16* __restrict__ CTX) {
  __shared__ __align__(16) u16 smem[16384 + 8192 + 4 * 2304];
  u16* Vlds = smem + 16384;
  const int hb = blockIdx.x;       // 0..63
  const int qt = 15 - blockIdx.y;  // heavy tiles dispatch first
  const int tid = threadIdx.x;
  const int lane = tid & 63, wave = tid >> 6;
  const int fr = lane & 15, fg = lane >> 4;
  u16* Plds = smem + 24576 + wave * 2304;
  const int qbase = qt * 128;
  const int wq0 = qbase + wave * 32;
  const size_t hOff = (size_t)hb * 2048 * 128;

  bf16x8 qf[2][4];
#pragma unroll
  for (int qb = 0; qb < 2; ++qb)
#pragma unroll
    for (int ks = 0; ks < 4; ++ks)
      qf[qb][ks] =
          *(const bf16x8*)(Qh + hOff + (size_t)(wq0 + qb * 16 + fr) * 128 + ks * 32 + fg * 8);

  f32x4 o[8][2] = {};
  float m[2] = {-1e30f, -1e30f}, lsum[2] = {0.f, 0.f};
  const int jend = 2 * (qt + 1);
  const int jmask = wq0 >> 6;

#define STAGE_K(j, kb)                                                       \
  do {                                                                       \
    _Pragma("unroll") for (int i_ = 0; i_ < 4; ++i_) {                       \
      int g_ = i_ * 256 + tid;                                               \
      int row_ = g_ >> 4, cg_ = g_ & 15;                                     \
      int gs_ = cg_ ^ (row_ & 7);                                            \
      gload_lds16(Kh + hOff + (size_t)((j)*64 + row_) * 128 + gs_ * 8,       \
                  smem + (kb)*8192 + g_ * 8);                                \
    }                                                                        \
  } while (0)
#define STAGE_V(j)                                                           \
  do {                                                                       \
    _Pragma("unroll") for (int i_ = 0; i_ < 4; ++i_) {                       \
      int g_ = i_ * 256 + tid;                                               \
      int row_ = g_ >> 3, cg_ = g_ & 7;                                      \
      int gs_ = cg_ ^ (row_ & 7);                                            \
      gload_lds16(VTh + hOff + (size_t)row_ * 2048 + (j)*64 + gs_ * 8,       \
                  Vlds + g_ * 8);                                            \
    }                                                                        \
  } while (0)

  STAGE_K(0, 0);  // 4 loads in flight

  for (int j = 0; j < jend; ++j) {
    const u16* Kl = smem + (j & 1) * 8192;
    STAGE_V(j);  // +4
    const bool pre = (j + 1 < jend);
    if (pre) {
      STAGE_K(j + 1, (j + 1) & 1);  // +4 (total 12 in flight)
      asm volatile("s_waitcnt vmcnt(8)" ::: "memory");  // K(j) landed
    } else {
      asm volatile("s_waitcnt vmcnt(4)" ::: "memory");  // K(j) landed
    }
    __builtin_amdgcn_s_barrier();  // K(j) published

    // ST[kv][q] = K @ Q^T
    f32x4 st[4][2] = {};
    __builtin_amdgcn_s_setprio(1);
#pragma unroll
    for (int ks = 0; ks < 4; ++ks) {
#pragma unroll
      for (int f = 0; f < 4; ++f) {
        bf16x8 kf = *(const bf16x8*)(Kl + (f * 16 + fr) * 128 +
                                     (((ks * 4 + fg) ^ (fr & 7)) * 8));
#pragma unroll
        for (int qb = 0; qb < 2; ++qb)
          st[f][qb] = __builtin_amdgcn_mfma_f32_16x16x32_bf16(kf, qf[qb][ks], st[f][qb], 0, 0, 0);
      }
    }
    __builtin_amdgcn_s_setprio(0);
    if (j >= jmask) {
#pragma unroll
      for (int f = 0; f < 4; ++f)
#pragma unroll
        for (int qb = 0; qb < 2; ++qb)
#pragma unroll
          for (int r = 0; r < 4; ++r) {
            int kv = j * 64 + f * 16 + fg * 4 + r;
            int q = wq0 + qb * 16 + fr;
            if (kv > q) st[f][qb][r] = -1e30f;
          }
    }
#pragma unroll
    for (int qb = 0; qb < 2; ++qb) {
      float pmax = -1e30f;
#pragma unroll
      for (int f = 0; f < 4; ++f)
#pragma unroll
        for (int r = 0; r < 4; ++r) pmax = fmaxf(pmax, st[f][qb][r]);
      pmax = fmaxf(pmax, __shfl_xor(pmax, 16));
      pmax = fmaxf(pmax, __shfl_xor(pmax, 32));
      // T13 defer-max
      if (!__all(pmax <= m[qb] + 8.0f)) {
        float mnew = fmaxf(m[qb], pmax);
        float factor = __expf(m[qb] - mnew);
        lsum[qb] *= factor;
#pragma unroll
        for (int db = 0; db < 8; ++db) o[db][qb] *= factor;
        m[qb] = mnew;
      }
      float psum = 0.f;
#pragma unroll
      for (int f = 0; f < 4; ++f) {
        float p0 = __expf(st[f][qb][0] - m[qb]);
        float p1 = __expf(st[f][qb][1] - m[qb]);
        float p2 = __expf(st[f][qb][2] - m[qb]);
        float p3 = __expf(st[f][qb][3] - m[qb]);
        psum += (p0 + p1) + (p2 + p3);
        u32 w0 = (u32)f2bf(p0) | ((u32)f2bf(p1) << 16);
        u32 w1 = (u32)f2bf(p2) | ((u32)f2bf(p3) << 16);
        *(uint2*)(Plds + (qb * 16 + fr) * 72 + f * 16 + fg * 4) = make_uint2(w0, w1);
      }
      psum += __shfl_xor(psum, 16);
      psum += __shfl_xor(psum, 32);
      lsum[qb] += psum;
    }
    // V(j) wait deferred to here: it was loading during QK+softmax
    if (pre) {
      asm volatile("s_waitcnt vmcnt(4)" ::: "memory");  // V(j) landed, K(j+1) flying
    } else {
      asm volatile("s_waitcnt vmcnt(0)" ::: "memory");
    }
    __builtin_amdgcn_s_barrier();  // V(j) published

    // ctx^T += V^T @ P
    __builtin_amdgcn_s_setprio(1);
#pragma unroll
    for (int ks2 = 0; ks2 < 2; ++ks2) {
      bf16x8 pf[2];
#pragma unroll
      for (int qb = 0; qb < 2; ++qb)
        pf[qb] = *(const bf16x8*)(Plds + (qb * 16 + fr) * 72 + ks2 * 32 + fg * 8);
#pragma unroll
      for (int db = 0; db < 8; ++db) {
        bf16x8 vf = *(const bf16x8*)(Vlds + (db * 16 + fr) * 64 +
                                     (((ks2 * 4 + fg) ^ (fr & 7)) * 8));
#pragma unroll
        for (int qb = 0; qb < 2; ++qb)
          o[db][qb] = __builtin_amdgcn_mfma_f32_16x16x32_bf16(vf, pf[qb], o[db][qb], 0, 0, 0);
      }
    }
    __builtin_amdgcn_s_setprio(0);
    __builtin_amdgcn_s_barrier();  // all waves done reading V(j)/K(j) before next overwrites
  }
#undef STAGE_K
#undef STAGE_V

  float inv[2] = {1.f / lsum[0], 1.f / lsum[1]};
  __syncthreads();
  u16* cst = smem + wave * 32 * 136;  // [32 q][136]
#pragma unroll
  for (int db = 0; db < 8; ++db)
#pragma unroll
    for (int qb = 0; qb < 2; ++qb) {
      u32 w0 = (u32)f2bf(o[db][qb][0] * inv[qb]) | ((u32)f2bf(o[db][qb][1] * inv[qb]) << 16);
      u32 w1 = (u32)f2bf(o[db][qb][2] * inv[qb]) | ((u32)f2bf(o[db][qb][3] * inv[qb]) << 16);
      *(uint2*)(cst + (qb * 16 + fr) * 136 + db * 16 + fg * 4) = make_uint2(w0, w1);
    }
  __syncthreads();
  const int b = hb >> 5, h = hb & 31;
#pragma unroll
  for (int i = 0; i < 8; ++i) {
    int slot = i * 256 + tid;
    int qr = slot >> 4, c = (slot & 15) * 8;
    *(uint4*)(CTX + (size_t)(b * 2048 + qbase + qr) * 4096 + h * 128 + c) =
        *(const uint4*)(smem + qr * 136 + c);
  }
}

// ---------------- launch ----------------
extern "C" void kernel_launch(void* const* d_in, const int* in_sizes, int n_in,
                              void* d_out, int out_size, void* d_ws, size_t ws_size,
                              hipStream_t stream) {
  const float* hidden = (const float*)d_in[0];
  const float* qkv_w = (const float*)d_in[1];
  const float* o_w = (const float*)d_in[2];
  float* out = (float*)d_out;
  if (ws_size < (256ull << 20)) return;  // need 256 MiB scratch
  char* ws = (char*)d_ws;
  u16* Xb    = (u16*)(ws + 0);               // [4096][4096]   32 MiB
  u16* WqkvT = (u16*)(ws + (32ull << 20));   // [12288][4096]  96 MiB
  u16* QKV   = (u16*)(ws + (128ull << 20));  // [4096][12288]  96 MiB
  u16* VTh   = (u16*)(ws + (224ull << 20));  // [64][128][2048] 32 MiB
  u16* Qh    = (u16*)(ws + (32ull << 20));   // reuse WqkvT region (dead after gemm1)
  u16* Kh    = (u16*)(ws + (64ull << 20));
  u16* WoT   = (u16*)(ws + (96ull << 20));   // [4096][4096] bf16; written after gemm1
  float* Trig = (float*)(ws + (224ull << 20)); // in VTh region: live k_trig->k_rope,
                                               // overwritten by k_vtrans (after k_rope)
  u16* CTX   = (u16*)(ws + 0);               // reuse Xb region

  k_trig<<<2048, 128, 0, stream>>>(Trig);
  k_f2bf<<<2048, 256, 0, stream>>>(hidden, Xb, 16777216 / 8);
  k_convT<<<dim3(64, 192), 256, 0, stream>>>(qkv_w, WqkvT, 12288, 4096);
  k_gemm256<true><<<768, 512, 0, stream>>>(Xb, WqkvT, QKV, 12288, 4096, 16);
  k_rope<<<4096, 256, 0, stream>>>(QKV, Trig, Qh, Kh);
  k_vtrans<<<dim3(64, 32), 256, 0, stream>>>(QKV, VTh);
  k_convT<<<dim3(64, 64), 256, 0, stream>>>(o_w, WoT, 4096, 4096);
  k_attn<<<dim3(64, 16), 256, 0, stream>>>(Qh, Kh, VTh, CTX);
  k_gemm256<false><<<256, 512, 0, stream>>>(CTX, WoT, out, 4096, 4096, 16);
}

// Round 10
// 654.840 us; speedup vs baseline: 1.0659x; 1.0659x over previous
//
#include <hip/hip_runtime.h>
#include <cstdint>
#include <cstddef>

using u16 = unsigned short;
using u32 = unsigned int;

typedef __bf16 bf16x8 __attribute__((ext_vector_type(8)));
typedef float f32x4 __attribute__((ext_vector_type(4)));

#define DEV static __device__ __forceinline__

DEV u16 f2bf(float f) {
  u32 u = __builtin_bit_cast(u32, f);
  u32 r = (u + 0x7fffu + ((u >> 16) & 1u)) >> 16;   // RNE
  return (u16)r;
}
DEV float bf2f(u16 u) { return __builtin_bit_cast(float, ((u32)u) << 16); }

DEV void gload_lds16(const void* g, void* l) {
  __builtin_amdgcn_global_load_lds(
      (__attribute__((address_space(1))) void*)(void*)g,
      (__attribute__((address_space(3))) void*)l, 16, 0, 0);
}

// ---------------- fp32 -> bf16 elementwise ----------------
__global__ __launch_bounds__(256) void k_f2bf(const float* __restrict__ in,
                                              u16* __restrict__ out, int n8) {
  int tid = blockIdx.x * 256 + threadIdx.x;
  int nt = gridDim.x * 256;
  for (int i = tid; i < n8; i += nt) {
    const float4* p = (const float4*)(in + (size_t)i * 8);
    float4 a = p[0], b = p[1];
    u32 w0 = (u32)f2bf(a.x) | ((u32)f2bf(a.y) << 16);
    u32 w1 = (u32)f2bf(a.z) | ((u32)f2bf(a.w) << 16);
    u32 w2 = (u32)f2bf(b.x) | ((u32)f2bf(b.y) << 16);
    u32 w3 = (u32)f2bf(b.z) | ((u32)f2bf(b.w) << 16);
    *(uint4*)(out + (size_t)i * 8) = make_uint4(w0, w1, w2, w3);
  }
}

// ------------- fp32 W[k][n] -> bf16 WT[n][k] (64x64 LDS tiles) -------------
__global__ __launch_bounds__(256) void k_convT(const float* __restrict__ W,
                                               u16* __restrict__ WT,
                                               int ncols, int krows) {
  __shared__ u16 tile[64 * 66];
  int r0 = blockIdx.x * 64, c0 = blockIdx.y * 64;
  int t = threadIdx.x;
#pragma unroll
  for (int i = 0; i < 4; ++i) {
    int slot = i * 256 + t;
    int r = slot >> 4, c = (slot & 15) * 4;
    float4 v = *(const float4*)(W + (size_t)(r0 + r) * ncols + c0 + c);
    tile[r * 66 + c] = f2bf(v.x);
    tile[r * 66 + c + 1] = f2bf(v.y);
    tile[r * 66 + c + 2] = f2bf(v.z);
    tile[r * 66 + c + 3] = f2bf(v.w);
  }
  __syncthreads();
#pragma unroll
  for (int i = 0; i < 2; ++i) {
    int slot = i * 256 + t;
    int c = slot >> 3, rr = (slot & 7) * 8;
    u32 w[4];
#pragma unroll
    for (int j = 0; j < 4; ++j) {
      u16 lo = tile[(rr + 2 * j) * 66 + c];
      u16 hi = tile[(rr + 2 * j + 1) * 66 + c];
      w[j] = (u32)lo | ((u32)hi << 16);
    }
    *(uint4*)(WT + (size_t)(c0 + c) * krows + r0 + rr) =
        make_uint4(w[0], w[1], w[2], w[3]);
  }
}

// =============== 256x256 8-phase bf16 GEMM (round-8 schedule) ===============
// MODE 0: plain f32 C-write. MODE 2: fused RoPE+relayout epilogue
// (Q/K -> Qh/Kh head-major with rope; V -> VTh transposed).
#define VM6 asm volatile("s_waitcnt vmcnt(6)" ::: "memory")
#define VM8 asm volatile("s_waitcnt vmcnt(8)" ::: "memory")
#define VM0 asm volatile("s_waitcnt vmcnt(0)" ::: "memory")

template <int MODE>
__global__ __launch_bounds__(512, 2) void k_gemm256(
    const u16* __restrict__ A, const u16* __restrict__ BT,
    void* __restrict__ Cout, int N, int K, int grid_m,
    const float* __restrict__ Trig, u16* __restrict__ Qh,
    u16* __restrict__ Kh, u16* __restrict__ VTh) {
  __shared__ __align__(16) u16 smem[65536];  // A: [0,32768), B: [32768,65536)
  const int nwg = gridDim.x;
  const int cpx = nwg >> 3;
  const int wg = (blockIdx.x & 7) * cpx + (blockIdx.x >> 3);
  const int row0 = (wg % grid_m) * 256;
  const int col0 = (wg / grid_m) * 256;
  const int tid = threadIdx.x;
  const int lane = tid & 63, wave = tid >> 6;
  const int wm = wave >> 2, wn = wave & 3;  // 2 x 4
  const int fr = lane & 15, fg = lane >> 4;
  const int NT = K >> 6;

  const int r_l0 = tid >> 3;
  const int gl = (tid & 7) ^ (r_l0 & 7);  // pre-swizzled logical granule

#define STAGE_A(b, h, s)                                                          \
  do {                                                                            \
    const u16* src_ = A + (size_t)(row0 + (h)*128 + r_l0) * K + (s)*64 + gl * 8;  \
    gload_lds16(src_, smem + (b)*16384 + (h)*8192 + tid * 8);                     \
    gload_lds16(src_ + (size_t)64 * K, smem + (b)*16384 + (h)*8192 + 4096 + tid * 8); \
  } while (0)
#define STAGE_B(b, h, s)                                                          \
  do {                                                                            \
    const u16* src_ = BT + (size_t)(col0 + (h)*128 + r_l0) * K + (s)*64 + gl * 8; \
    gload_lds16(src_, smem + 32768 + (b)*16384 + (h)*8192 + tid * 8);             \
    gload_lds16(src_ + (size_t)64 * K, smem + 32768 + (b)*16384 + (h)*8192 + 4096 + tid * 8); \
  } while (0)

  const int aBase = (wm * 64 + fr) * 64;
  const int bBase = (wn * 32 + fr) * 64;
  const int sg0 = ((fg) ^ (fr & 7)) * 8;
  const int sg1 = ((4 + fg) ^ (fr & 7)) * 8;
#define LDA(buf, mh, m, kk) \
  (*(const bf16x8*)(&smem[(buf)*16384 + aBase + (mh)*8192 + (m)*1024 + ((kk) ? sg1 : sg0)]))
#define LDB(buf, nh, n, kk) \
  (*(const bf16x8*)(&smem[32768 + (buf)*16384 + bBase + (nh)*8192 + (n)*1024 + ((kk) ? sg1 : sg0)]))

  bf16x8 a[4][2], b0[2][2], b1[2][2];
  f32x4 acc[2][2][4][2] = {};

  // Single barrier per phase: {reads; stage; barrier; MFMA; wait}.
#define PHASE(buf, mh, nh, RDA, RDB, BP, STG, WT)                                  \
  {                                                                                \
    if (RDA) {                                                                     \
      _Pragma("unroll") for (int m_ = 0; m_ < 4; ++m_) {                           \
        a[m_][0] = LDA(buf, mh, m_, 0);                                            \
        a[m_][1] = LDA(buf, mh, m_, 1);                                            \
      }                                                                            \
    }                                                                              \
    if (RDB) {                                                                     \
      _Pragma("unroll") for (int n_ = 0; n_ < 2; ++n_) {                           \
        BP[n_][0] = LDB(buf, nh, n_, 0);                                           \
        BP[n_][1] = LDB(buf, nh, n_, 1);                                           \
      }                                                                            \
    }                                                                              \
    STG;                                                                           \
    __builtin_amdgcn_s_barrier();                                                  \
    __builtin_amdgcn_s_setprio(1);                                                 \
    _Pragma("unroll") for (int m_ = 0; m_ < 4; ++m_) {                             \
      _Pragma("unroll") for (int n_ = 0; n_ < 2; ++n_) {                           \
        acc[mh][nh][m_][n_] = __builtin_amdgcn_mfma_f32_16x16x32_bf16(             \
            a[m_][0], BP[n_][0], acc[mh][nh][m_][n_], 0, 0, 0);                    \
        acc[mh][nh][m_][n_] = __builtin_amdgcn_mfma_f32_16x16x32_bf16(             \
            a[m_][1], BP[n_][1], acc[mh][nh][m_][n_], 0, 0, 0);                    \
      }                                                                            \
    }                                                                              \
    __builtin_amdgcn_s_setprio(0);                                                 \
    WT;                                                                            \
  }

  STAGE_A(0, 0, 0); STAGE_B(0, 0, 0);
  STAGE_A(0, 1, 0); STAGE_B(0, 1, 0);
  STAGE_A(1, 0, 1); STAGE_B(1, 0, 1);
  VM8;
  __builtin_amdgcn_s_barrier();

  const int nIt = NT >> 1;
  for (int it = 0; it < nIt; ++it) {
    const int T = 2 * it;
    const int s2 = (T + 2 < NT) ? T + 2 : T;
    const int s3 = (T + 3 < NT) ? T + 3 : T;
    PHASE(0, 0, 0, true,  true,  b0, { STAGE_A(1, 1, T + 1); }, VM6);
    PHASE(0, 0, 1, false, true,  b1, { STAGE_B(1, 1, T + 1); }, ((void)0));
    PHASE(0, 1, 0, true,  false, b0, { STAGE_A(0, 0, s2); },    ((void)0));
    PHASE(0, 1, 1, false, false, b1, { STAGE_B(0, 0, s2); },    VM8);
    PHASE(1, 0, 0, true,  true,  b0, { STAGE_A(0, 1, s2); },    VM6);
    PHASE(1, 0, 1, false, true,  b1, { STAGE_B(0, 1, s2); },    ((void)0));
    PHASE(1, 1, 0, true,  false, b0, { STAGE_A(1, 0, s3); },    ((void)0));
    PHASE(1, 1, 1, false, false, b1, { STAGE_B(1, 0, s3); },    VM8);
  }
  VM0;

  if (MODE == 0) {
#pragma unroll
    for (int mh = 0; mh < 2; ++mh)
#pragma unroll
      for (int nh = 0; nh < 2; ++nh)
#pragma unroll
        for (int m = 0; m < 4; ++m) {
          const int growb = row0 + mh * 128 + wm * 64 + m * 16 + fg * 4;
#pragma unroll
          for (int rr = 0; rr < 4; ++rr) {
#pragma unroll
            for (int n = 0; n < 2; ++n) {
              const int gcol = col0 + nh * 128 + wn * 32 + n * 16 + fr;
              ((float*)Cout)[(size_t)(growb + rr) * N + gcol] = acc[mh][nh][m][n][rr];
            }
          }
        }
  } else {
    // Fused RoPE + head-major relayout epilogue. Two 128-col (1 head) passes.
    const int bb = row0 >> 11;
    const int s0 = row0 & 2047;
    const float qscale = 0.08838834764831845f;
    for (int p = 0; p < 2; ++p) {
      __syncthreads();  // prior LDS readers (GEMM or pass p-1) done
      // scatter acc[.][p][.][.] -> E[256][132] (conflict-free: fg spreads banks)
#pragma unroll
      for (int mh = 0; mh < 2; ++mh)
#pragma unroll
        for (int m = 0; m < 4; ++m)
#pragma unroll
          for (int n = 0; n < 2; ++n) {
            const int rbase = mh * 128 + wm * 64 + m * 16 + fg * 4;
            const int col = wn * 32 + n * 16 + fr;
#pragma unroll
            for (int rr = 0; rr < 4; ++rr)
              smem[(rbase + rr) * 132 + col] = f2bf(acc[mh][p][m][n][rr]);
          }
      __syncthreads();
      const int cb = col0 + p * 128;
      const int reg = cb >> 12;          // 0=Q, 1=K, 2=V
      const int h = (cb & 4095) >> 7;    // head 0..31
      if (reg < 2) {
        const int rloc = tid >> 1, half = tid & 1;
        const int s = s0 + rloc;
        const u16* Erow = smem + rloc * 132;
        const float sc = (reg == 0) ? qscale : 1.0f;
        u16* dst = ((reg == 0) ? Qh : Kh) +
                   ((size_t)(bb * 32 + h) * 2048 + s) * 128 + half * 64;
        const float* tc = Trig + (size_t)s * 128;
#pragma unroll
        for (int jv = 0; jv < 8; ++jv) {
          uint4 v1 = *(const uint4*)(Erow + jv * 8);
          uint4 v2 = *(const uint4*)(Erow + 64 + jv * 8);
          const u16* x1 = (const u16*)&v1;
          const u16* x2 = (const u16*)&v2;
          u16 ob[8];
#pragma unroll
          for (int j = 0; j < 8; ++j) {
            int d = jv * 8 + j;
            float c = tc[d], sv = tc[64 + d];
            float av = bf2f(x1[j]), dv2 = bf2f(x2[j]);
            float o = half ? (dv2 * c + av * sv) : (av * c - dv2 * sv);
            ob[j] = f2bf(o * sc);
          }
          *(uint4*)(dst + jv * 8) = *(const uint4*)ob;
        }
      } else {
        const int dv = tid >> 2, sq = (tid & 3) * 64;
        u16* dst = VTh + ((size_t)(bb * 32 + h) * 128 + dv) * 2048 + s0 + sq;
#pragma unroll
        for (int w = 0; w < 8; ++w) {
          u32 pk[4];
#pragma unroll
          for (int q = 0; q < 4; ++q) {
            int sA = sq + w * 8 + q * 2;
            u16 lo = smem[sA * 132 + dv];
            u16 hi = smem[(sA + 1) * 132 + dv];
            pk[q] = (u32)lo | ((u32)hi << 16);
          }
          *(uint4*)(dst + w * 8) = make_uint4(pk[0], pk[1], pk[2], pk[3]);
        }
      }
    }
  }
#undef PHASE
#undef LDA
#undef LDB
#undef STAGE_A
#undef STAGE_B
}

// ---------------- RoPE trig table: T[s][0..63]=cos, [64..127]=sin ----------------
__global__ __launch_bounds__(128) void k_trig(float* __restrict__ T) {
  const int s = blockIdx.x;
  const int t = threadIdx.x;
  float inv = powf(10000.0f, -(float)(t & 63) * (1.0f / 64.0f));
  float ang = (float)s * inv;
  T[(size_t)s * 128 + t] = (t < 64) ? cosf(ang) : sinf(ang);
}

// ---------------- causal flash attention, QBLK=128, pipelined staging ----------------
__global__ __launch_bounds__(256, 2) void k_attn(const u16* __restrict__ Qh,
                                                 const u16* __restrict__ Kh,
                                                 const u16* __restrict__ VTh,
                                                 u16* __restrict__ CTX) {
  __shared__ __align__(16) u16 smem[16384 + 8192 + 4 * 2304];
  u16* Vlds = smem + 16384;
  const int hb = blockIdx.x;       // 0..63
  const int qt = 15 - blockIdx.y;  // heavy tiles dispatch first
  const int tid = threadIdx.x;
  const int lane = tid & 63, wave = tid >> 6;
  const int fr = lane & 15, fg = lane >> 4;
  u16* Plds = smem + 24576 + wave * 2304;
  const int qbase = qt * 128;
  const int wq0 = qbase + wave * 32;
  const size_t hOff = (size_t)hb * 2048 * 128;

  bf16x8 qf[2][4];
#pragma unroll
  for (int qb = 0; qb < 2; ++qb)
#pragma unroll
    for (int ks = 0; ks < 4; ++ks)
      qf[qb][ks] =
          *(const bf16x8*)(Qh + hOff + (size_t)(wq0 + qb * 16 + fr) * 128 + ks * 32 + fg * 8);

  f32x4 o[8][2] = {};
  float m[2] = {-1e30f, -1e30f}, lsum[2] = {0.f, 0.f};
  const int jend = 2 * (qt + 1);
  const int jmask = wq0 >> 6;

#define STAGE_K(j, kb)                                                       \
  do {                                                                       \
    _Pragma("unroll") for (int i_ = 0; i_ < 4; ++i_) {                       \
      int g_ = i_ * 256 + tid;                                               \
      int row_ = g_ >> 4, cg_ = g_ & 15;                                     \
      int gs_ = cg_ ^ (row_ & 7);                                            \
      gload_lds16(Kh + hOff + (size_t)((j)*64 + row_) * 128 + gs_ * 8,       \
                  smem + (kb)*8192 + g_ * 8);                                \
    }                                                                        \
  } while (0)
#define STAGE_V(j)                                                           \
  do {                                                                       \
    _Pragma("unroll") for (int i_ = 0; i_ < 4; ++i_) {                       \
      int g_ = i_ * 256 + tid;                                               \
      int row_ = g_ >> 3, cg_ = g_ & 7;                                      \
      int gs_ = cg_ ^ (row_ & 7);                                            \
      gload_lds16(VTh + hOff + (size_t)row_ * 2048 + (j)*64 + gs_ * 8,       \
                  Vlds + g_ * 8);                                            \
    }                                                                        \
  } while (0)

  STAGE_K(0, 0);  // 4 loads in flight

  for (int j = 0; j < jend; ++j) {
    const u16* Kl = smem + (j & 1) * 8192;
    STAGE_V(j);  // +4
    const bool pre = (j + 1 < jend);
    if (pre) {
      STAGE_K(j + 1, (j + 1) & 1);  // +4 (total 12 in flight)
      asm volatile("s_waitcnt vmcnt(8)" ::: "memory");  // K(j) landed
    } else {
      asm volatile("s_waitcnt vmcnt(4)" ::: "memory");  // K(j) landed
    }
    __builtin_amdgcn_s_barrier();  // K(j) published

    // ST[kv][q] = K @ Q^T
    f32x4 st[4][2] = {};
    __builtin_amdgcn_s_setprio(1);
#pragma unroll
    for (int ks = 0; ks < 4; ++ks) {
#pragma unroll
      for (int f = 0; f < 4; ++f) {
        bf16x8 kf = *(const bf16x8*)(Kl + (f * 16 + fr) * 128 +
                                     (((ks * 4 + fg) ^ (fr & 7)) * 8));
#pragma unroll
        for (int qb = 0; qb < 2; ++qb)
          st[f][qb] = __builtin_amdgcn_mfma_f32_16x16x32_bf16(kf, qf[qb][ks], st[f][qb], 0, 0, 0);
      }
    }
    __builtin_amdgcn_s_setprio(0);
    if (j >= jmask) {
#pragma unroll
      for (int f = 0; f < 4; ++f)
#pragma unroll
        for (int qb = 0; qb < 2; ++qb)
#pragma unroll
          for (int r = 0; r < 4; ++r) {
            int kv = j * 64 + f * 16 + fg * 4 + r;
            int q = wq0 + qb * 16 + fr;
            if (kv > q) st[f][qb][r] = -1e30f;
          }
    }
#pragma unroll
    for (int qb = 0; qb < 2; ++qb) {
      float pmax = -1e30f;
#pragma unroll
      for (int f = 0; f < 4; ++f)
#pragma unroll
        for (int r = 0; r < 4; ++r) pmax = fmaxf(pmax, st[f][qb][r]);
      pmax = fmaxf(pmax, __shfl_xor(pmax, 16));
      pmax = fmaxf(pmax, __shfl_xor(pmax, 32));
      // T13 defer-max
      if (!__all(pmax <= m[qb] + 8.0f)) {
        float mnew = fmaxf(m[qb], pmax);
        float factor = __expf(m[qb] - mnew);
        lsum[qb] *= factor;
#pragma unroll
        for (int db = 0; db < 8; ++db) o[db][qb] *= factor;
        m[qb] = mnew;
      }
      float psum = 0.f;
#pragma unroll
      for (int f = 0; f < 4; ++f) {
        float p0 = __expf(st[f][qb][0] - m[qb]);
        float p1 = __expf(st[f][qb][1] - m[qb]);
        float p2 = __expf(st[f][qb][2] - m[qb]);
        float p3 = __expf(st[f][qb][3] - m[qb]);
        psum += (p0 + p1) + (p2 + p3);
        u32 w0 = (u32)f2bf(p0) | ((u32)f2bf(p1) << 16);
        u32 w1 = (u32)f2bf(p2) | ((u32)f2bf(p3) << 16);
        *(uint2*)(Plds + (qb * 16 + fr) * 72 + f * 16 + fg * 4) = make_uint2(w0, w1);
      }
      psum += __shfl_xor(psum, 16);
      psum += __shfl_xor(psum, 32);
      lsum[qb] += psum;
    }
    // V(j) wait deferred to here: it was loading during QK+softmax
    if (pre) {
      asm volatile("s_waitcnt vmcnt(4)" ::: "memory");  // V(j) landed, K(j+1) flying
    } else {
      asm volatile("s_waitcnt vmcnt(0)" ::: "memory");
    }
    __builtin_amdgcn_s_barrier();  // V(j) published

    // ctx^T += V^T @ P
    __builtin_amdgcn_s_setprio(1);
#pragma unroll
    for (int ks2 = 0; ks2 < 2; ++ks2) {
      bf16x8 pf[2];
#pragma unroll
      for (int qb = 0; qb < 2; ++qb)
        pf[qb] = *(const bf16x8*)(Plds + (qb * 16 + fr) * 72 + ks2 * 32 + fg * 8);
#pragma unroll
      for (int db = 0; db < 8; ++db) {
        bf16x8 vf = *(const bf16x8*)(Vlds + (db * 16 + fr) * 64 +
                                     (((ks2 * 4 + fg) ^ (fr & 7)) * 8));
#pragma unroll
        for (int qb = 0; qb < 2; ++qb)
          o[db][qb] = __builtin_amdgcn_mfma_f32_16x16x32_bf16(vf, pf[qb], o[db][qb], 0, 0, 0);
      }
    }
    __builtin_amdgcn_s_setprio(0);
    __builtin_amdgcn_s_barrier();  // all waves done reading V(j)/K(j) before next overwrites
  }
#undef STAGE_K
#undef STAGE_V

  float inv[2] = {1.f / lsum[0], 1.f / lsum[1]};
  __syncthreads();
  u16* cst = smem + wave * 32 * 136;  // [32 q][136]
#pragma unroll
  for (int db = 0; db < 8; ++db)
#pragma unroll
    for (int qb = 0; qb < 2; ++qb) {
      u32 w0 = (u32)f2bf(o[db][qb][0] * inv[qb]) | ((u32)f2bf(o[db][qb][1] * inv[qb]) << 16);
      u32 w1 = (u32)f2bf(o[db][qb][2] * inv[qb]) | ((u32)f2bf(o[db][qb][3] * inv[qb]) << 16);
      *(uint2*)(cst + (qb * 16 + fr) * 136 + db * 16 + fg * 4) = make_uint2(w0, w1);
    }
  __syncthreads();
  const int b = hb >> 5, h = hb & 31;
#pragma unroll
  for (int i = 0; i < 8; ++i) {
    int slot = i * 256 + tid;
    int qr = slot >> 4, c = (slot & 15) * 8;
    *(uint4*)(CTX + (size_t)(b * 2048 + qbase + qr) * 4096 + h * 128 + c) =
        *(const uint4*)(smem + qr * 136 + c);
  }
}

// ---------------- launch ----------------
extern "C" void kernel_launch(void* const* d_in, const int* in_sizes, int n_in,
                              void* d_out, int out_size, void* d_ws, size_t ws_size,
                              hipStream_t stream) {
  const float* hidden = (const float*)d_in[0];
  const float* qkv_w = (const float*)d_in[1];
  const float* o_w = (const float*)d_in[2];
  float* out = (float*)d_out;
  if (ws_size < (256ull << 20)) return;  // need 256 MiB scratch
  char* ws = (char*)d_ws;
  // Lifetimes: Xb/WqkvT live through gemm1; Qh/Kh/VTh written by gemm1 epilogue,
  // read by attn; Trig written by k_trig, read by gemm1, dead after; WoT reuses
  // the WqkvT region AFTER gemm1; CTX reuses Xb region after gemm1.
  u16* Xb    = (u16*)(ws + 0);                 // [4096][4096]    32 MiB
  u16* WqkvT = (u16*)(ws + (32ull << 20));     // [12288][4096]   96 MiB
  u16* Qh    = (u16*)(ws + (128ull << 20));    // [64][2048][128] 32 MiB
  u16* Kh    = (u16*)(ws + (160ull << 20));    // 32 MiB
  u16* VTh   = (u16*)(ws + (192ull << 20));    // [64][128][2048] 32 MiB
  float* Trig = (float*)(ws + (224ull << 20)); // [2048][128] f32  1 MiB
  u16* WoT   = (u16*)(ws + (32ull << 20));     // after gemm1 (WqkvT dead)
  u16* CTX   = (u16*)(ws + 0);                 // after gemm1 (Xb dead)

  k_trig<<<2048, 128, 0, stream>>>(Trig);
  k_f2bf<<<2048, 256, 0, stream>>>(hidden, Xb, 16777216 / 8);
  k_convT<<<dim3(64, 192), 256, 0, stream>>>(qkv_w, WqkvT, 12288, 4096);
  k_gemm256<2><<<768, 512, 0, stream>>>(Xb, WqkvT, nullptr, 12288, 4096, 16,
                                        Trig, Qh, Kh, VTh);
  k_convT<<<dim3(64, 64), 256, 0, stream>>>(o_w, WoT, 4096, 4096);
  k_attn<<<dim3(64, 16), 256, 0, stream>>>(Qh, Kh, VTh, CTX);
  k_gemm256<0><<<256, 512, 0, stream>>>(CTX, WoT, out, 4096, 4096, 16,
                                        nullptr, nullptr, nullptr, nullptr);
}